// Round 9
// baseline (110.765 us; speedup 1.0000x reference)
//
#include <hip/hip_runtime.h>
#include <math.h>
#include <stdint.h>

#define NTRAIN 16384
#define DIM 64
#define ODIM 8
#define BATCH 8192
#define LOG2E 1.4426950408889634f

typedef float f32x16 __attribute__((ext_vector_type(16)));
typedef short short8 __attribute__((ext_vector_type(8)));
typedef unsigned short u16;

// float -> bf16 bits, RNE (no NaN in this data)
static __device__ __forceinline__ u16 f2bf(float f) {
  unsigned u = __builtin_bit_cast(unsigned, f);
  u += 0x7FFFu + ((u >> 16) & 1u);
  return (u16)(u >> 16);
}
static __device__ __forceinline__ float bf2f(u16 b) {
  unsigned u = ((unsigned)b) << 16;
  return __builtin_bit_cast(float, u);
}

static __device__ __forceinline__ f32x16 mfma32(short8 a, short8 b, f32x16 c) {
  return __builtin_amdgcn_mfma_f32_32x32x16_bf16(a, b, c, 0, 0, 0);
}
static __device__ __forceinline__ unsigned pkbf(float a, float b) {
  unsigned d;
  asm("v_cvt_pk_bf16_f32 %0, %1, %2" : "=v"(d) : "v"(a), "v"(b));
  return d;
}
// 2^(-x)
static __device__ __forceinline__ float ex2n(float x) {
  float r;
  asm("v_exp_f32 %0, -%1" : "=v"(r) : "v"(x));
  return r;
}
static __device__ __forceinline__ void plswap(unsigned& a, unsigned& b) {
  asm("v_permlane32_swap_b32 %0, %1" : "+v"(a), "+v"(b));
}

// ---------------------------------------------------------------------------
// Fused prep:
//   X fragments = hi/lo bf16 of 2*gamma_n^2*x[n][k]  (gamma = beta*log2e)
//   V fragments = [1 | y | 0pad]
//   b2[m] = |a_m|^2 ;  gx2[n] = gamma^2*|x_n|^2 ;  g2[n] = gamma^2
// ---------------------------------------------------------------------------
__global__ __launch_bounds__(256) void k_prep(
    const float* __restrict__ batches, const float* __restrict__ xt,
    const float* __restrict__ yt, const float* __restrict__ beta,
    u16* __restrict__ xh, u16* __restrict__ xl, u16* __restrict__ yv,
    float* __restrict__ b2, float* __restrict__ gx2, float* __restrict__ g2) {
  int tid = blockIdx.x * 256 + threadIdx.x;

  if (tid < (NTRAIN / 32) * 4 * 64) {  // X fragments
    int frag = tid >> 6, lane = tid & 63;
    int ntile = frag >> 2, ks = frag & 3;
    int lr = lane & 31, hi = lane >> 5;
    int n = ntile * 32 + lr;
    float g = beta[n] * LOG2E;
    float s2g = 2.0f * g * g;
    const float* src = xt + (size_t)n * DIM + ks * 16 + hi * 8;
    unsigned h[8], l[8];
#pragma unroll
    for (int j = 0; j < 8; ++j) {
      float v = s2g * src[j];
      u16 hb = f2bf(v);
      h[j] = hb;
      l[j] = f2bf(v - bf2f(hb));
    }
    uint4 uh, ul;
    uh.x = h[0] | (h[1] << 16); uh.y = h[2] | (h[3] << 16);
    uh.z = h[4] | (h[5] << 16); uh.w = h[6] | (h[7] << 16);
    ul.x = l[0] | (l[1] << 16); ul.y = l[2] | (l[3] << 16);
    ul.z = l[4] | (l[5] << 16); ul.w = l[6] | (l[7] << 16);
    ((uint4*)xh)[(size_t)frag * 64 + lane] = uh;
    ((uint4*)xl)[(size_t)frag * 64 + lane] = ul;
    return;
  }
  tid -= (NTRAIN / 32) * 4 * 64;

  if (tid < (NTRAIN / 16) * 64) {  // V fragments
    int frag = tid >> 6, lane = tid & 63;
    int col = lane & 31, hi = lane >> 5;
    int n = frag * 16 + hi * 8;
    unsigned e[8];
#pragma unroll
    for (int j = 0; j < 8; ++j) {
      float v = (col == 0) ? 1.0f : ((col < 9) ? yt[(size_t)(n + j) * ODIM + (col - 1)] : 0.0f);
      e[j] = f2bf(v);
    }
    uint4 u;
    u.x = e[0] | (e[1] << 16); u.y = e[2] | (e[3] << 16);
    u.z = e[4] | (e[5] << 16); u.w = e[6] | (e[7] << 16);
    ((uint4*)yv)[(size_t)frag * 64 + lane] = u;
    return;
  }
  tid -= (NTRAIN / 16) * 64;

  if (tid < BATCH + NTRAIN) {  // row norms
    const float* row = (tid < BATCH) ? batches + (size_t)tid * DIM
                                     : xt + (size_t)(tid - BATCH) * DIM;
    const float4* r4 = (const float4*)row;
    float s0 = 0.f, s1 = 0.f, s2 = 0.f, s3 = 0.f;
#pragma unroll
    for (int q = 0; q < DIM / 4; ++q) {
      float4 v = r4[q];
      s0 = fmaf(v.x, v.x, s0); s1 = fmaf(v.y, v.y, s1);
      s2 = fmaf(v.z, v.z, s2); s3 = fmaf(v.w, v.w, s3);
    }
    float nrm = (s0 + s1) + (s2 + s3);
    if (tid < BATCH) {
      b2[tid] = nrm;
    } else {
      int n = tid - BATCH;
      float g = beta[n] * LOG2E;
      gx2[n] = nrm * g * g;
    }
    return;
  }
  tid -= BATCH + NTRAIN;

  if (tid < NTRAIN) {
    float g = beta[tid] * LOG2E;
    g2[tid] = g * g;
  }
}

// ---------------------------------------------------------------------------
// Pass 1. Block = 4 waves x 32 m-rows. Ring-4 LDS staging (stage-ahead 2),
// counted vmcnt(2) + plain s_barrier per phase (no vmcnt(0) drain in loop).
// Per slab: dual MFMA chains; sA init = -(g2*b2 + g2*x2) so -(sA+sB) = g2*sq;
// w = exp2(-sqrt(|sA+sB|)); in-register bf16 pack; 2 PV MFMAs.
// ---------------------------------------------------------------------------
// Stage one 32-n slab (xh 4KB + xl 4KB = 8 x 1KB chunks) into ring buffer.
// Wave w stages chunks 2w, 2w+1. LDS dest is wave-uniform base (+lane*16 HW).
#define STAGE1(buf_, nbv)                                                     \
  {                                                                           \
    _Pragma("unroll")                                                         \
    for (int q = 0; q < 2; ++q) {                                             \
      const int ch = w * 2 + q;                                               \
      const u16* gsrc = (ch < 4) ? xh : xl;                                   \
      const size_t goff = ((size_t)((nbv) >> 5) * 4 + (ch & 3)) * 1024 +      \
                          (size_t)lane * 16;                                  \
      __builtin_amdgcn_global_load_lds(                                       \
          (const __attribute__((address_space(1))) unsigned int*)(            \
              (const char*)gsrc + goff),                                      \
          (__attribute__((address_space(3))) unsigned int*)                   \
              &lds[(buf_) * 8192 + ch * 1024],                                \
          16, 0, 0);                                                          \
    }                                                                         \
  }

__global__ __launch_bounds__(256, 3) void grnn_pass1(
    const u16* __restrict__ xh, const u16* __restrict__ xl,
    const u16* __restrict__ yv,
    const float* __restrict__ batches,
    const float* __restrict__ g2, const float* __restrict__ gx2,
    const float* __restrict__ b2,
    float* __restrict__ partial, int chunk_n) {
  __shared__ char lds[4 * 8192];
  const int w = threadIdx.x >> 6, lane = threadIdx.x & 63;
  const int lr = lane & 31, hi = lane >> 5;
  const int mrow0 = blockIdx.x * 128 + w * 32;
  const int c = blockIdx.y;
  const int n0 = c * chunk_n;
  const int nslab = chunk_n / 32;

  // Batch fragments (B-operand): hi/lo, 4 ksteps; -b2 scalar.
  short8 AH[4], AL[4];
  const int mrow = mrow0 + lr;
  const float mb2 = -b2[mrow];
#pragma unroll
  for (int ks = 0; ks < 4; ++ks) {
    const float* src = batches + (size_t)mrow * DIM + ks * 16 + hi * 8;
    float4 v0 = *(const float4*)src;
    float4 v1 = *(const float4*)(src + 4);
    float vv[8] = {v0.x, v0.y, v0.z, v0.w, v1.x, v1.y, v1.z, v1.w};
    short8 hh, ll;
#pragma unroll
    for (int j = 0; j < 8; ++j) {
      u16 hb = f2bf(vv[j]);
      hh[j] = (short)hb;
      ll[j] = (short)f2bf(vv[j] - bf2f(hb));
    }
    AH[ks] = hh;
    AL[ks] = ll;
  }

  f32x16 pv;
#pragma unroll
  for (int r = 0; r < 16; ++r) pv[r] = 0.f;

  const uint4* yv4 = (const uint4*)yv;

  STAGE1(0, n0)
  STAGE1(1, n0 + 32)

  for (int s = 0; s < nslab; ++s) {
    const int nb = n0 + s * 32;
    const char* lb = &lds[(s & 3) * 8192];

    // Tail constants for slab s: issue BEFORE the prefetch STAGE so our
    // vmcnt(2) (and the compiler's auto-waits) never drain the prefetch.
    float4 g2q[4], gx2q[4];
#pragma unroll
    for (int g = 0; g < 4; ++g) {
      gx2q[g] = *(const float4*)&gx2[nb + 8 * g + 4 * hi];
      g2q[g] = *(const float4*)&g2[nb + 8 * g + 4 * hi];
    }
    short8 V0 = __builtin_bit_cast(short8, yv4[(size_t)(nb >> 4) * 64 + lane]);
    short8 V1 = __builtin_bit_cast(short8, yv4[(size_t)(nb >> 4) * 64 + 64 + lane]);

    if (s + 2 < nslab) {
      STAGE1((s + 2) & 3, nb + 64)
      asm volatile("s_waitcnt vmcnt(2)" ::: "memory");  // drains slab s+1 & older
    } else {
      asm volatile("s_waitcnt vmcnt(0)" ::: "memory");  // loop tail
    }
    __builtin_amdgcn_s_barrier();
    __builtin_amdgcn_sched_barrier(0);

    short8 XH[4], XL[4];
#pragma unroll
    for (int ks = 0; ks < 4; ++ks) {
      XH[ks] = __builtin_bit_cast(short8,
                                  *(const uint4*)&lb[ks * 1024 + lane * 16]);
      XL[ks] = __builtin_bit_cast(
          short8, *(const uint4*)&lb[4096 + ks * 1024 + lane * 16]);
    }

    f32x16 sA, sB;
#pragma unroll
    for (int r = 0; r < 16; ++r) {
      sA[r] = fmaf(mb2, g2q[r >> 2][r & 3], -gx2q[r >> 2][r & 3]);
      sB[r] = 0.f;
    }
    __builtin_amdgcn_s_setprio(1);
#pragma unroll
    for (int ks = 0; ks < 4; ++ks) {
      sA = mfma32(XH[ks], AH[ks], sA);
      sB = mfma32(XL[ks], AH[ks], sB);
      sB = mfma32(XH[ks], AL[ks], sB);
    }
    __builtin_amdgcn_s_setprio(0);

    // -(sA+sB) = g2*sq >= 0 ;  w = exp2(-sqrt(|sA+sB|))
    unsigned U[8];
#pragma unroll
    for (int p = 0; p < 8; ++p) {
      const int i0 = 2 * p, i1 = 2 * p + 1;
      float d0 = __builtin_amdgcn_sqrtf(fabsf(sA[i0] + sB[i0]));
      float d1 = __builtin_amdgcn_sqrtf(fabsf(sA[i1] + sB[i1]));
      U[p] = pkbf(ex2n(d0), ex2n(d1));
    }
    plswap(U[0], U[2]); plswap(U[1], U[3]);
    plswap(U[4], U[6]); plswap(U[5], U[7]);
    uint4 a1 = {U[0], U[1], U[2], U[3]};
    uint4 a2 = {U[4], U[5], U[6], U[7]};
    pv = mfma32(__builtin_bit_cast(short8, a1), V0, pv);
    pv = mfma32(__builtin_bit_cast(short8, a2), V1, pv);
  }

  // Epilogue: col 0 = sum(w), cols 1..8 = sum(w*y).
  float* pc = partial + (size_t)c * 9 * BATCH;
  if (lr < 9) {
#pragma unroll
    for (int r = 0; r < 16; ++r)
      pc[(size_t)lr * BATCH + (mrow0 + (r & 3) + 8 * (r >> 2) + 4 * hi)] = pv[r];
  }
}

// ---------------------------------------------------------------------------
// Pass 2: reduce chunks, divide.
// ---------------------------------------------------------------------------
__global__ __launch_bounds__(256) void grnn_pass2(const float* __restrict__ partial,
                                                  float* __restrict__ out, int nc) {
  int b = blockIdx.x * 256 + threadIdx.x;
  float s1 = 0.f;
  float s2[ODIM];
#pragma unroll
  for (int j = 0; j < ODIM; ++j) s2[j] = 0.f;
  for (int cc = 0; cc < nc; ++cc) {
    const float* p = partial + (size_t)cc * 9 * BATCH;
    s1 += p[b];
#pragma unroll
    for (int j = 0; j < ODIM; ++j) s2[j] += p[(size_t)(j + 1) * BATCH + b];
  }
  const float inv = 1.f / s1;
#pragma unroll
  for (int j = 0; j < ODIM; ++j) out[(size_t)b * ODIM + j] = s2[j] * inv;
}

// ---------------------------------------------------------------------------
extern "C" void kernel_launch(void* const* d_in, const int* in_sizes, int n_in,
                              void* d_out, int out_size, void* d_ws, size_t ws_size,
                              hipStream_t stream) {
  const float* batches = (const float*)d_in[0];  // [8192, 64]
  const float* xt      = (const float*)d_in[1];  // [16384, 64]
  const float* yt      = (const float*)d_in[2];  // [16384, 8]
  const float* beta    = (const float*)d_in[3];  // [1, 16384]
  float* out = (float*)d_out;                    // [8192, 8]

  const size_t xh_b  = (size_t)NTRAIN * DIM * 2;            // 2 MB each
  const size_t yv_b  = (size_t)(NTRAIN / 16) * 64 * 16;     // 1 MB
  const size_t gx2_b = (size_t)NTRAIN * 4;
  const size_t g2_b  = (size_t)NTRAIN * 4;
  const size_t b2_b  = (size_t)BATCH * 4;
  const size_t fixed = 2 * xh_b + yv_b + gx2_b + g2_b + b2_b;
  const size_t per_chunk = (size_t)9 * BATCH * 4;           // 288 KB

  int nc = 32;
  while (nc > 1 && fixed + (size_t)nc * per_chunk > ws_size) nc >>= 1;
  const int chunk_n = NTRAIN / nc;  // multiple of 64 for all nc in {1..32}

  char* p = (char*)d_ws;
  u16* xh = (u16*)p;      p += xh_b;
  u16* xl = (u16*)p;      p += xh_b;
  u16* yv = (u16*)p;      p += yv_b;
  float* gx2 = (float*)p; p += gx2_b;
  float* g2 = (float*)p;  p += g2_b;
  float* b2 = (float*)p;  p += b2_b;
  float* partial = (float*)p;

  const int prep_threads = (NTRAIN / 32) * 4 * 64 + (NTRAIN / 16) * 64 +
                           (BATCH + NTRAIN) + NTRAIN;
  k_prep<<<(prep_threads + 255) / 256, 256, 0, stream>>>(
      batches, xt, yt, beta, xh, xl, yv, b2, gx2, g2);
  grnn_pass1<<<dim3(BATCH / 128, nc), 256, 0, stream>>>(
      xh, xl, yv, batches, g2, gx2, b2, partial, chunk_n);
  grnn_pass2<<<BATCH / 256, 256, 0, stream>>>(partial, out, nc);
}

// Round 10
// 74.923 us; speedup vs baseline: 1.4784x; 1.4784x over previous
//
#include <hip/hip_runtime.h>
#include <math.h>
#include <stdint.h>

#define NTRAIN 16384
#define DIM 64
#define ODIM 8
#define BATCH 8192
#define LOG2E 1.4426950408889634f

typedef float f32x16 __attribute__((ext_vector_type(16)));
typedef short short8 __attribute__((ext_vector_type(8)));
typedef _Float16 f16x8 __attribute__((ext_vector_type(8)));
typedef unsigned short u16;

// float -> bf16 bits, RNE
static __device__ __forceinline__ u16 f2bf(float f) {
  unsigned u = __builtin_bit_cast(unsigned, f);
  u += 0x7FFFu + ((u >> 16) & 1u);
  return (u16)(u >> 16);
}
// float -> fp16 bits, RNE (v_cvt_f16_f32)
static __device__ __forceinline__ u16 f2h(float f) {
  return __builtin_bit_cast(u16, (_Float16)f);
}
static __device__ __forceinline__ float h2f(u16 h) {
  return (float)__builtin_bit_cast(_Float16, h);
}

static __device__ __forceinline__ f32x16 mfma_bf(short8 a, short8 b, f32x16 c) {
  return __builtin_amdgcn_mfma_f32_32x32x16_bf16(a, b, c, 0, 0, 0);
}
static __device__ __forceinline__ f32x16 mfma_h(f16x8 a, f16x8 b, f32x16 c) {
  return __builtin_amdgcn_mfma_f32_32x32x16_f16(a, b, c, 0, 0, 0);
}
static __device__ __forceinline__ unsigned pkbf(float a, float b) {
  unsigned d;
  asm("v_cvt_pk_bf16_f32 %0, %1, %2" : "=v"(d) : "v"(a), "v"(b));
  return d;
}
// 2^(-x)
static __device__ __forceinline__ float ex2n(float x) {
  float r;
  asm("v_exp_f32 %0, -%1" : "=v"(r) : "v"(x));
  return r;
}
static __device__ __forceinline__ void plswap(unsigned& a, unsigned& b) {
  asm("v_permlane32_swap_b32 %0, %1" : "+v"(a), "+v"(b));
}

// ---------------------------------------------------------------------------
// k_norm: x2[n] = |x_n|^2 ; b2[m] = |a_m|^2
// ---------------------------------------------------------------------------
__global__ __launch_bounds__(256) void k_norm(
    const float* __restrict__ batches, const float* __restrict__ xt,
    float* __restrict__ b2, float* __restrict__ x2) {
  int i = blockIdx.x * 256 + threadIdx.x;
  if (i >= BATCH + NTRAIN) return;
  const float* row = (i < BATCH) ? batches + (size_t)i * DIM
                                 : xt + (size_t)(i - BATCH) * DIM;
  const float4* r4 = (const float4*)row;
  float s0 = 0.f, s1 = 0.f, s2 = 0.f, s3 = 0.f;
#pragma unroll
  for (int q = 0; q < DIM / 4; ++q) {
    float4 v = r4[q];
    s0 = fmaf(v.x, v.x, s0); s1 = fmaf(v.y, v.y, s1);
    s2 = fmaf(v.z, v.z, s2); s3 = fmaf(v.w, v.w, s3);
  }
  float nrm = (s0 + s1) + (s2 + s3);
  if (i < BATCH) b2[i] = nrm;
  else x2[i - BATCH] = nrm;
}

// ---------------------------------------------------------------------------
// k_frag: per 32-n tile, 5 fp16 A-fragments (32x32x16 f16):
//   f=0..3 : 2*gamma_n^2 * x[n][k], k = f*16 + (lane>>5)*8 + j
//   f=4    : norm kstep, lanes<32, slots [gx2_h, gx2_l, g2_h, g2_h, g2_l, 0..]
// plus bf16 V = [1 | y | 0pad] B-fragments (unchanged).
// ---------------------------------------------------------------------------
__global__ __launch_bounds__(256) void k_frag(
    const float* __restrict__ xt, const float* __restrict__ yt,
    const float* __restrict__ beta, const float* __restrict__ x2,
    u16* __restrict__ xf, u16* __restrict__ yv) {
  int tid = blockIdx.x * 256 + threadIdx.x;

  if (tid < (NTRAIN / 32) * 5 * 64) {
    int fg = tid >> 6, lane = tid & 63;
    int tile = fg / 5, f = fg % 5;
    int lr = lane & 31, hi = lane >> 5;
    uint4 u = {0, 0, 0, 0};
    if (f == 4) {
      if (hi == 0) {
        int n = tile * 32 + lr;
        float g = beta[n] * LOG2E;
        float g2v = g * g;
        float gx2v = g2v * x2[n];
        u16 xh = f2h(gx2v);
        u16 xl = f2h(gx2v - h2f(xh));
        u16 gh = f2h(g2v);
        u16 gl = f2h(g2v - h2f(gh));
        u.x = (unsigned)xh | ((unsigned)xl << 16);
        u.y = (unsigned)gh | ((unsigned)gh << 16);
        u.z = (unsigned)gl;
      }
    } else {
      int n = tile * 32 + lr;
      float g = beta[n] * LOG2E;
      float s2g = 2.0f * g * g;
      const float* src = xt + (size_t)n * DIM + f * 16 + hi * 8;
      unsigned e[8];
#pragma unroll
      for (int j = 0; j < 8; ++j) e[j] = f2h(s2g * src[j]);
      u.x = e[0] | (e[1] << 16); u.y = e[2] | (e[3] << 16);
      u.z = e[4] | (e[5] << 16); u.w = e[6] | (e[7] << 16);
    }
    ((uint4*)xf)[(size_t)fg * 64 + lane] = u;
    return;
  }
  tid -= (NTRAIN / 32) * 5 * 64;

  if (tid < (NTRAIN / 16) * 64) {  // V fragments (bf16)
    int frag = tid >> 6, lane = tid & 63;
    int col = lane & 31, hi = lane >> 5;
    int n = frag * 16 + hi * 8;
    unsigned e[8];
#pragma unroll
    for (int j = 0; j < 8; ++j) {
      float v = (col == 0) ? 1.0f : ((col < 9) ? yt[(size_t)(n + j) * ODIM + (col - 1)] : 0.0f);
      e[j] = f2bf(v);
    }
    uint4 u;
    u.x = e[0] | (e[1] << 16); u.y = e[2] | (e[3] << 16);
    u.z = e[4] | (e[5] << 16); u.w = e[6] | (e[7] << 16);
    ((uint4*)yv)[(size_t)frag * 64 + lane] = u;
  }
}

// ---------------------------------------------------------------------------
// Pass 1: fp16 S-GEMM (5 MFMAs incl. norm-fold kstep), bf16 PV.
// Barrier-free: each wave register-double-buffers its X slab from L2.
// sA = 2g2*a.x - g2*x2 - g2*b2 = -(gamma*d)^2 ; w = exp2(-sqrt(|sA|)).
// ---------------------------------------------------------------------------
#define LOAD5(X_, nbv)                                                        \
  {                                                                           \
    const size_t fb_ = (size_t)((nbv) >> 5) * 5;                              \
    _Pragma("unroll")                                                         \
    for (int f = 0; f < 5; ++f) X_[f] = xf4[(fb_ + f) * 64 + lane];           \
  }

#define COMPUTE(X_, nbv)                                                      \
  {                                                                           \
    short8 V0 = __builtin_bit_cast(short8,                                    \
                                   yv4[(size_t)((nbv) >> 4) * 64 + lane]);    \
    short8 V1 = __builtin_bit_cast(                                           \
        short8, yv4[(size_t)((nbv) >> 4) * 64 + 64 + lane]);                  \
    f32x16 sA;                                                                \
    _Pragma("unroll")                                                         \
    for (int r = 0; r < 16; ++r) sA[r] = 0.f;                                 \
    __builtin_amdgcn_s_setprio(1);                                            \
    sA = mfma_h(__builtin_bit_cast(f16x8, X_[4]), AN, sA);                    \
    _Pragma("unroll")                                                         \
    for (int ks = 0; ks < 4; ++ks)                                            \
      sA = mfma_h(__builtin_bit_cast(f16x8, X_[ks]), AH[ks], sA);             \
    __builtin_amdgcn_s_setprio(0);                                            \
    unsigned U[8];                                                            \
    _Pragma("unroll")                                                         \
    for (int p = 0; p < 8; ++p) {                                             \
      float d0 = __builtin_amdgcn_sqrtf(fabsf(sA[2 * p]));                    \
      float d1 = __builtin_amdgcn_sqrtf(fabsf(sA[2 * p + 1]));                \
      U[p] = pkbf(ex2n(d0), ex2n(d1));                                        \
    }                                                                         \
    plswap(U[0], U[2]); plswap(U[1], U[3]);                                   \
    plswap(U[4], U[6]); plswap(U[5], U[7]);                                   \
    uint4 a1 = {U[0], U[1], U[2], U[3]};                                      \
    uint4 a2 = {U[4], U[5], U[6], U[7]};                                      \
    pv = mfma_bf(__builtin_bit_cast(short8, a1), V0, pv);                     \
    pv = mfma_bf(__builtin_bit_cast(short8, a2), V1, pv);                     \
  }

__global__ __launch_bounds__(256, 4) void grnn_pass1(
    const u16* __restrict__ xf, const u16* __restrict__ yv,
    const float* __restrict__ batches, const float* __restrict__ b2,
    float* __restrict__ partial, int chunk_n) {
  const int lane = threadIdx.x & 63;
  const int lr = lane & 31, hi = lane >> 5;
  const int mrow0 = blockIdx.x * 128 + (threadIdx.x >> 6) * 32;
  const int c = blockIdx.y;
  const int n0 = c * chunk_n;
  const int nslab = chunk_n / 32;

  // Batch fragments (B-operand), fp16 single: 4 ksteps + norm fragment.
  f16x8 AH[4], AN;
  const int mrow = mrow0 + lr;
#pragma unroll
  for (int ks = 0; ks < 4; ++ks) {
    const float* src = batches + (size_t)mrow * DIM + ks * 16 + hi * 8;
    float4 v0 = *(const float4*)src;
    float4 v1 = *(const float4*)(src + 4);
    AH[ks][0] = (_Float16)v0.x; AH[ks][1] = (_Float16)v0.y;
    AH[ks][2] = (_Float16)v0.z; AH[ks][3] = (_Float16)v0.w;
    AH[ks][4] = (_Float16)v1.x; AH[ks][5] = (_Float16)v1.y;
    AH[ks][6] = (_Float16)v1.z; AH[ks][7] = (_Float16)v1.w;
  }
#pragma unroll
  for (int j = 0; j < 8; ++j) AN[j] = (_Float16)0.0f;
  if (hi == 0) {
    float b2v = b2[mrow];
    _Float16 bh = (_Float16)b2v;
    _Float16 bl = (_Float16)(b2v - (float)bh);
    AN[0] = (_Float16)(-1.0f);
    AN[1] = (_Float16)(-1.0f);
    AN[2] = -bh;
    AN[3] = -bl;
    AN[4] = -bh;
  }

  f32x16 pv;
#pragma unroll
  for (int r = 0; r < 16; ++r) pv[r] = 0.f;

  const uint4* xf4 = (const uint4*)xf;
  const uint4* yv4 = (const uint4*)yv;

  uint4 Xa[5], Xb[5];
  LOAD5(Xa, n0)
  for (int s = 0; s < nslab; s += 2) {
    const int nb = n0 + s * 32;
    if (s + 1 < nslab) LOAD5(Xb, nb + 32)
    COMPUTE(Xa, nb)
    if (s + 2 < nslab) LOAD5(Xa, nb + 64)
    if (s + 1 < nslab) COMPUTE(Xb, nb + 32)
  }

  // Epilogue: col 0 = sum(w), cols 1..8 = sum(w*y).
  float* pc = partial + (size_t)c * 9 * BATCH;
  if (lr < 9) {
#pragma unroll
    for (int r = 0; r < 16; ++r)
      pc[(size_t)lr * BATCH + (mrow0 + (r & 3) + 8 * (r >> 2) + 4 * hi)] = pv[r];
  }
}

// ---------------------------------------------------------------------------
// Pass 2: reduce chunks, divide.
// ---------------------------------------------------------------------------
__global__ __launch_bounds__(256) void grnn_pass2(const float* __restrict__ partial,
                                                  float* __restrict__ out, int nc) {
  int b = blockIdx.x * 256 + threadIdx.x;
  float s1 = 0.f;
  float s2[ODIM];
#pragma unroll
  for (int j = 0; j < ODIM; ++j) s2[j] = 0.f;
  for (int cc = 0; cc < nc; ++cc) {
    const float* p = partial + (size_t)cc * 9 * BATCH;
    s1 += p[b];
#pragma unroll
    for (int j = 0; j < ODIM; ++j) s2[j] += p[(size_t)(j + 1) * BATCH + b];
  }
  const float inv = 1.f / s1;
#pragma unroll
  for (int j = 0; j < ODIM; ++j) out[(size_t)b * ODIM + j] = s2[j] * inv;
}

// ---------------------------------------------------------------------------
extern "C" void kernel_launch(void* const* d_in, const int* in_sizes, int n_in,
                              void* d_out, int out_size, void* d_ws, size_t ws_size,
                              hipStream_t stream) {
  const float* batches = (const float*)d_in[0];  // [8192, 64]
  const float* xt      = (const float*)d_in[1];  // [16384, 64]
  const float* yt      = (const float*)d_in[2];  // [16384, 8]
  const float* beta    = (const float*)d_in[3];  // [1, 16384]
  float* out = (float*)d_out;                    // [8192, 8]

  const size_t xf_b = (size_t)(NTRAIN / 32) * 5 * 1024;    // 2.625 MB
  const size_t yv_b = (size_t)(NTRAIN / 16) * 64 * 16;     // 1 MB
  const size_t x2_b = (size_t)NTRAIN * 4;
  const size_t b2_b = (size_t)BATCH * 4;
  const size_t fixed = xf_b + yv_b + x2_b + b2_b;
  const size_t per_chunk = (size_t)9 * BATCH * 4;          // 288 KB

  int nc = 32;
  while (nc > 1 && fixed + (size_t)nc * per_chunk > ws_size) nc >>= 1;
  const int chunk_n = NTRAIN / nc;  // multiple of 64 for all nc in {1..32}

  char* p = (char*)d_ws;
  u16* xf = (u16*)p;      p += xf_b;
  u16* yv = (u16*)p;      p += yv_b;
  float* x2 = (float*)p;  p += x2_b;
  float* b2 = (float*)p;  p += b2_b;
  float* partial = (float*)p;

  k_norm<<<(BATCH + NTRAIN + 255) / 256, 256, 0, stream>>>(batches, xt, b2, x2);
  const int frag_threads = (NTRAIN / 32) * 5 * 64 + (NTRAIN / 16) * 64;
  k_frag<<<(frag_threads + 255) / 256, 256, 0, stream>>>(xt, yt, beta, x2, xf, yv);
  grnn_pass1<<<dim3(BATCH / 128, nc), 256, 0, stream>>>(
      xf, yv, batches, b2, partial, chunk_n);
  grnn_pass2<<<BATCH / 256, 256, 0, stream>>>(partial, out, nc);
}

// Round 11
// 70.565 us; speedup vs baseline: 1.5697x; 1.0618x over previous
//
#include <hip/hip_runtime.h>
#include <math.h>
#include <stdint.h>

#define NTRAIN 16384
#define DIM 64
#define ODIM 8
#define BATCH 8192
#define LOG2E 1.4426950408889634f

typedef float f32x16 __attribute__((ext_vector_type(16)));
typedef short short8 __attribute__((ext_vector_type(8)));
typedef _Float16 f16x8 __attribute__((ext_vector_type(8)));
typedef unsigned short u16;

// float -> bf16 bits, RNE
static __device__ __forceinline__ u16 f2bf(float f) {
  unsigned u = __builtin_bit_cast(unsigned, f);
  u += 0x7FFFu + ((u >> 16) & 1u);
  return (u16)(u >> 16);
}
// float -> fp16 bits, RNE
static __device__ __forceinline__ u16 f2h(float f) {
  return __builtin_bit_cast(u16, (_Float16)f);
}
static __device__ __forceinline__ float h2f(u16 h) {
  return (float)__builtin_bit_cast(_Float16, h);
}

static __device__ __forceinline__ f32x16 mfma_bf(short8 a, short8 b, f32x16 c) {
  return __builtin_amdgcn_mfma_f32_32x32x16_bf16(a, b, c, 0, 0, 0);
}
static __device__ __forceinline__ f32x16 mfma_h(f16x8 a, f16x8 b, f32x16 c) {
  return __builtin_amdgcn_mfma_f32_32x32x16_f16(a, b, c, 0, 0, 0);
}
static __device__ __forceinline__ unsigned pkbf(float a, float b) {
  unsigned d;
  asm("v_cvt_pk_bf16_f32 %0, %1, %2" : "=v"(d) : "v"(a), "v"(b));
  return d;
}
// 2^(-x)
static __device__ __forceinline__ float ex2n(float x) {
  float r;
  asm("v_exp_f32 %0, -%1" : "=v"(r) : "v"(x));
  return r;
}
static __device__ __forceinline__ void plswap(unsigned& a, unsigned& b) {
  asm("v_permlane32_swap_b32 %0, %1" : "+v"(a), "+v"(b));
}

// ---------------------------------------------------------------------------
// k_frag: per 32-n tile, 5 fp16 A-fragments (32x32x16 f16):
//   f=0..3 : 2*gamma_n^2 * x[n][k], k = f*16 + (lane>>5)*8 + j
//   f=4    : norm kstep (lanes hi==0): [gx2_h, gx2_l, g2_h, g2_h, g2_l, 0..]
//            (x2 computed inline from xt row)
// plus bf16 V = [1 | y | 0pad] B-fragments.
// ---------------------------------------------------------------------------
__global__ __launch_bounds__(256) void k_frag(
    const float* __restrict__ xt, const float* __restrict__ yt,
    const float* __restrict__ beta,
    u16* __restrict__ xf, u16* __restrict__ yv) {
  int tid = blockIdx.x * 256 + threadIdx.x;

  if (tid < (NTRAIN / 32) * 5 * 64) {
    int fg = tid >> 6, lane = tid & 63;
    int tile = fg / 5, f = fg % 5;
    int lr = lane & 31, hi = lane >> 5;
    uint4 u = {0, 0, 0, 0};
    if (f == 4) {
      if (hi == 0) {
        int n = tile * 32 + lr;
        float g = beta[n] * LOG2E;
        float g2v = g * g;
        // x2 inline
        const float4* r4 = (const float4*)(xt + (size_t)n * DIM);
        float s0 = 0.f, s1 = 0.f, s2 = 0.f, s3 = 0.f;
#pragma unroll
        for (int q = 0; q < DIM / 4; ++q) {
          float4 v = r4[q];
          s0 = fmaf(v.x, v.x, s0); s1 = fmaf(v.y, v.y, s1);
          s2 = fmaf(v.z, v.z, s2); s3 = fmaf(v.w, v.w, s3);
        }
        float gx2v = g2v * ((s0 + s1) + (s2 + s3));
        u16 xh = f2h(gx2v);
        u16 xl = f2h(gx2v - h2f(xh));
        u16 gh = f2h(g2v);
        u16 gl = f2h(g2v - h2f(gh));
        u.x = (unsigned)xh | ((unsigned)xl << 16);
        u.y = (unsigned)gh | ((unsigned)gh << 16);
        u.z = (unsigned)gl;
      }
    } else {
      int n = tile * 32 + lr;
      float g = beta[n] * LOG2E;
      float s2g = 2.0f * g * g;
      const float* src = xt + (size_t)n * DIM + f * 16 + hi * 8;
      unsigned e[8];
#pragma unroll
      for (int j = 0; j < 8; ++j) e[j] = f2h(s2g * src[j]);
      u.x = e[0] | (e[1] << 16); u.y = e[2] | (e[3] << 16);
      u.z = e[4] | (e[5] << 16); u.w = e[6] | (e[7] << 16);
    }
    ((uint4*)xf)[(size_t)fg * 64 + lane] = u;
    return;
  }
  tid -= (NTRAIN / 32) * 5 * 64;

  if (tid < (NTRAIN / 16) * 64) {  // V fragments (bf16)
    int frag = tid >> 6, lane = tid & 63;
    int col = lane & 31, hi = lane >> 5;
    int n = frag * 16 + hi * 8;
    unsigned e[8];
#pragma unroll
    for (int j = 0; j < 8; ++j) {
      float v = (col == 0) ? 1.0f : ((col < 9) ? yt[(size_t)(n + j) * ODIM + (col - 1)] : 0.0f);
      e[j] = f2bf(v);
    }
    uint4 u;
    u.x = e[0] | (e[1] << 16); u.y = e[2] | (e[3] << 16);
    u.z = e[4] | (e[5] << 16); u.w = e[6] | (e[7] << 16);
    ((uint4*)yv)[(size_t)frag * 64 + lane] = u;
  }
}

// ---------------------------------------------------------------------------
// Pass 1: fp16 S-GEMM (5 MFMAs incl. norm-fold kstep), bf16 PV. Barrier-free,
// register-double-buffered X slabs. b2 computed in-register (permlane pair
// reduce). XCD c-locality swizzle: each XCD works on 4 c-slices so its L2
// holds only ~330KB of xf (+yv slice + batches) -> slab loads are L2 hits.
// ---------------------------------------------------------------------------
#define LOAD5(X_, nbv)                                                        \
  {                                                                           \
    const size_t fb_ = (size_t)((nbv) >> 5) * 5;                              \
    _Pragma("unroll")                                                         \
    for (int f = 0; f < 5; ++f) X_[f] = xf4[(fb_ + f) * 64 + lane];           \
  }

#define COMPUTE(X_, nbv)                                                      \
  {                                                                           \
    short8 V0 = __builtin_bit_cast(short8,                                    \
                                   yv4[(size_t)((nbv) >> 4) * 64 + lane]);    \
    short8 V1 = __builtin_bit_cast(                                           \
        short8, yv4[(size_t)((nbv) >> 4) * 64 + 64 + lane]);                  \
    f32x16 sA;                                                                \
    _Pragma("unroll")                                                         \
    for (int r = 0; r < 16; ++r) sA[r] = 0.f;                                 \
    __builtin_amdgcn_s_setprio(1);                                            \
    sA = mfma_h(__builtin_bit_cast(f16x8, X_[4]), AN, sA);                    \
    _Pragma("unroll")                                                         \
    for (int ks = 0; ks < 4; ++ks)                                            \
      sA = mfma_h(__builtin_bit_cast(f16x8, X_[ks]), AH[ks], sA);             \
    __builtin_amdgcn_s_setprio(0);                                            \
    unsigned U[8];                                                            \
    _Pragma("unroll")                                                         \
    for (int p = 0; p < 8; ++p) {                                             \
      float d0 = __builtin_amdgcn_sqrtf(fabsf(sA[2 * p]));                    \
      float d1 = __builtin_amdgcn_sqrtf(fabsf(sA[2 * p + 1]));                \
      U[p] = pkbf(ex2n(d0), ex2n(d1));                                        \
    }                                                                         \
    plswap(U[0], U[2]); plswap(U[1], U[3]);                                   \
    plswap(U[4], U[6]); plswap(U[5], U[7]);                                   \
    uint4 a1 = {U[0], U[1], U[2], U[3]};                                      \
    uint4 a2 = {U[4], U[5], U[6], U[7]};                                      \
    pv = mfma_bf(__builtin_bit_cast(short8, a1), V0, pv);                     \
    pv = mfma_bf(__builtin_bit_cast(short8, a2), V1, pv);                     \
  }

__global__ __launch_bounds__(256, 4) void grnn_pass1(
    const u16* __restrict__ xf, const u16* __restrict__ yv,
    const float* __restrict__ batches,
    float* __restrict__ partial, int chunk_n, int nc) {
  const int lane = threadIdx.x & 63;
  const int lr = lane & 31, hi = lane >> 5;

  // XCD c-locality swizzle (bijective; XCD id ~ bid%8 round-robin heuristic).
  int mt, c;
  if (nc == 32) {
    const int bid = blockIdx.x;
    const int xcd = bid & 7;
    const int q = bid >> 3;          // 0..255
    c = xcd + 8 * (q & 3);           // 4 c-slices per XCD
    mt = q >> 2;                     // 0..63
  } else {
    mt = blockIdx.x % (BATCH / 128);
    c = blockIdx.x / (BATCH / 128);
  }
  const int mrow0 = mt * 128 + (threadIdx.x >> 6) * 32;
  const int n0 = c * chunk_n;
  const int nslab = chunk_n / 32;

  // Batch fragments (B-operand), fp16: 4 ksteps; b2 computed in-register.
  f16x8 AH[4], AN;
  const int mrow = mrow0 + lr;
  float ssum = 0.f;
#pragma unroll
  for (int ks = 0; ks < 4; ++ks) {
    const float* src = batches + (size_t)mrow * DIM + ks * 16 + hi * 8;
    float4 v0 = *(const float4*)src;
    float4 v1 = *(const float4*)(src + 4);
    AH[ks][0] = (_Float16)v0.x; AH[ks][1] = (_Float16)v0.y;
    AH[ks][2] = (_Float16)v0.z; AH[ks][3] = (_Float16)v0.w;
    AH[ks][4] = (_Float16)v1.x; AH[ks][5] = (_Float16)v1.y;
    AH[ks][6] = (_Float16)v1.z; AH[ks][7] = (_Float16)v1.w;
    ssum = fmaf(v0.x, v0.x, ssum); ssum = fmaf(v0.y, v0.y, ssum);
    ssum = fmaf(v0.z, v0.z, ssum); ssum = fmaf(v0.w, v0.w, ssum);
    ssum = fmaf(v1.x, v1.x, ssum); ssum = fmaf(v1.y, v1.y, ssum);
    ssum = fmaf(v1.z, v1.z, ssum); ssum = fmaf(v1.w, v1.w, ssum);
  }
  // partner (lane^32) holds the other 32 elements of this row
  unsigned ua = __builtin_bit_cast(unsigned, ssum), ub = ua;
  plswap(ua, ub);
  const float b2v =
      __builtin_bit_cast(float, ua) + __builtin_bit_cast(float, ub);

#pragma unroll
  for (int j = 0; j < 8; ++j) AN[j] = (_Float16)0.0f;
  if (hi == 0) {
    _Float16 bh = (_Float16)b2v;
    _Float16 bl = (_Float16)(b2v - (float)bh);
    AN[0] = (_Float16)(-1.0f);
    AN[1] = (_Float16)(-1.0f);
    AN[2] = -bh;
    AN[3] = -bl;
    AN[4] = -bh;
  }

  f32x16 pv;
#pragma unroll
  for (int r = 0; r < 16; ++r) pv[r] = 0.f;

  const uint4* xf4 = (const uint4*)xf;
  const uint4* yv4 = (const uint4*)yv;

  uint4 Xa[5], Xb[5];
  LOAD5(Xa, n0)
  for (int s = 0; s < nslab; s += 2) {
    const int nb = n0 + s * 32;
    if (s + 1 < nslab) LOAD5(Xb, nb + 32)
    COMPUTE(Xa, nb)
    if (s + 2 < nslab) LOAD5(Xa, nb + 64)
    if (s + 1 < nslab) COMPUTE(Xb, nb + 32)
  }

  // Epilogue: col 0 = sum(w), cols 1..8 = sum(w*y).
  float* pc = partial + (size_t)c * 9 * BATCH;
  if (lr < 9) {
#pragma unroll
    for (int r = 0; r < 16; ++r)
      pc[(size_t)lr * BATCH + (mrow0 + (r & 3) + 8 * (r >> 2) + 4 * hi)] = pv[r];
  }
}

// ---------------------------------------------------------------------------
// Pass 2: reduce chunks, divide.
// ---------------------------------------------------------------------------
__global__ __launch_bounds__(256) void grnn_pass2(const float* __restrict__ partial,
                                                  float* __restrict__ out, int nc) {
  int b = blockIdx.x * 256 + threadIdx.x;
  float s1 = 0.f;
  float s2[ODIM];
#pragma unroll
  for (int j = 0; j < ODIM; ++j) s2[j] = 0.f;
  for (int cc = 0; cc < nc; ++cc) {
    const float* p = partial + (size_t)cc * 9 * BATCH;
    s1 += p[b];
#pragma unroll
    for (int j = 0; j < ODIM; ++j) s2[j] += p[(size_t)(j + 1) * BATCH + b];
  }
  const float inv = 1.f / s1;
#pragma unroll
  for (int j = 0; j < ODIM; ++j) out[(size_t)b * ODIM + j] = s2[j] * inv;
}

// ---------------------------------------------------------------------------
extern "C" void kernel_launch(void* const* d_in, const int* in_sizes, int n_in,
                              void* d_out, int out_size, void* d_ws, size_t ws_size,
                              hipStream_t stream) {
  const float* batches = (const float*)d_in[0];  // [8192, 64]
  const float* xt      = (const float*)d_in[1];  // [16384, 64]
  const float* yt      = (const float*)d_in[2];  // [16384, 8]
  const float* beta    = (const float*)d_in[3];  // [1, 16384]
  float* out = (float*)d_out;                    // [8192, 8]

  const size_t xf_b = (size_t)(NTRAIN / 32) * 5 * 1024;    // 2.625 MB
  const size_t yv_b = (size_t)(NTRAIN / 16) * 64 * 16;     // 1 MB
  const size_t fixed = xf_b + yv_b;
  const size_t per_chunk = (size_t)9 * BATCH * 4;          // 288 KB

  int nc = 32;
  while (nc > 1 && fixed + (size_t)nc * per_chunk > ws_size) nc >>= 1;
  const int chunk_n = NTRAIN / nc;  // multiple of 64 for all nc in {1..32}

  char* p = (char*)d_ws;
  u16* xf = (u16*)p;      p += xf_b;
  u16* yv = (u16*)p;      p += yv_b;
  float* partial = (float*)p;

  const int frag_threads = (NTRAIN / 32) * 5 * 64 + (NTRAIN / 16) * 64;
  k_frag<<<(frag_threads + 255) / 256, 256, 0, stream>>>(xt, yt, beta, xf, yv);
  grnn_pass1<<<(BATCH / 128) * nc, 256, 0, stream>>>(
      xf, yv, batches, partial, chunk_n, nc);
  grnn_pass2<<<BATCH / 256, 256, 0, stream>>>(partial, out, nc);
}